// Round 5
// baseline (1685.424 us; speedup 1.0000x reference)
//
#include <hip/hip_runtime.h>
#include <math.h>

// ---------------------------------------------------------------------------
// MyNet: two 1024x1024x3 images -> 3x3 matrix.
// R5: coding z-split 4 (img x og-half16) + __launch_bounds__(256,4) to force
//     <=128 VGPR (4 waves/SIMD; 140 VGPR was same band as 252 -> 2 waves).
//     pm512 reverted to 1px/thread in-thread finish (LDS-partial version was
//     +58us overhead) + launch_bounds cap + imm-offset loads.
// ---------------------------------------------------------------------------

__global__ void fuse_weights_kernel(const float* __restrict__ enc_w,
                                    const float* __restrict__ enc_b,
                                    const float* __restrict__ embed_w,
                                    const float* __restrict__ embed_b,
                                    float* __restrict__ weff_t,
                                    float* __restrict__ beff) {
    int t = threadIdx.x;
    for (int idx = t; idx < 27 * 32; idx += blockDim.x) {
        int r = idx >> 5, o = idx & 31;
        float s = 0.f;
        for (int k = 0; k < 24; ++k) s += embed_w[o * 24 + k] * enc_w[k * 27 + r];
        weff_t[idx] = s;
    }
    if (t < 32) {
        float s = embed_b[t];
        for (int k = 0; k < 24; ++k) s += embed_w[t * 24 + k] * enc_b[k];
        beff[t] = s;
    }
}

// Fused enc+embed 3x3 conv (3->32) + maxpool2 -> c (512^2), plus fused 2x2
// shfl maxpool -> p (256^2). z = img*2 + og_half (16 ch per launch slice).
__global__ __launch_bounds__(256, 4) void coding_kernel(
    const float* __restrict__ x1, const float* __restrict__ x2,
    const float* __restrict__ weff_t, const float* __restrict__ beff,
    float* __restrict__ c1, float* __restrict__ c2,
    float* __restrict__ p1, float* __restrict__ p2) {
    __shared__ float swT[27 * 16];  // [27][16] this og half
    __shared__ float sb[16];
    int img = blockIdx.z >> 1, og = blockIdx.z & 1;
    int tx = threadIdx.x, ty = threadIdx.y;
    int tid = ty * 16 + tx;
    for (int i = tid; i < 27 * 16; i += 256) {
        int r = i >> 4, o = i & 15;
        swT[i] = weff_t[r * 32 + og * 16 + o];
    }
    if (tid < 16) sb[tid] = beff[og * 16 + tid];
    __syncthreads();
    const float* x = img ? x2 : x1;
    float* c = img ? c2 : c1;
    float* p = img ? p2 : p1;
    int h = blockIdx.y * 16 + ty, w = blockIdx.x * 16 + tx;
    int Y = 2 * h, X = 2 * w;
    float in[3][4][4];
    bool interior_blk = (blockIdx.x > 0 && blockIdx.x < 31 &&
                         blockIdx.y > 0 && blockIdx.y < 31);
    if (interior_blk) {
#pragma unroll
        for (int ci = 0; ci < 3; ++ci)
#pragma unroll
            for (int yy = 0; yy < 4; ++yy) {
                const float* row = x + ci * 1048576 + (Y - 1 + yy) * 1024 + X - 1;
#pragma unroll
                for (int xx = 0; xx < 4; ++xx) in[ci][yy][xx] = row[xx];
            }
    } else {
#pragma unroll
        for (int ci = 0; ci < 3; ++ci)
#pragma unroll
            for (int yy = 0; yy < 4; ++yy)
#pragma unroll
                for (int xx = 0; xx < 4; ++xx) {
                    int gy = Y - 1 + yy, gx = X - 1 + xx;
                    in[ci][yy][xx] =
                        (gy >= 0 && gy < 1024 && gx >= 0 && gx < 1024)
                            ? x[ci * 1048576 + gy * 1024 + gx]
                            : 0.f;
                }
    }
    int pix = h * 512 + w;
    int ppix = (h >> 1) * 256 + (w >> 1);
    bool pwrite = (((tx | ty) & 1) == 0);
#pragma unroll 1
    for (int oc = 0; oc < 2; ++oc) {  // two 8-channel chunks of this half
        float acc[4][8];
#pragma unroll
        for (int pq = 0; pq < 4; ++pq)
#pragma unroll
            for (int oo = 0; oo < 8; ++oo) acc[pq][oo] = sb[oc * 8 + oo];
#pragma unroll
        for (int ci = 0; ci < 3; ++ci)
#pragma unroll
            for (int ky = 0; ky < 3; ++ky)
#pragma unroll
                for (int kx = 0; kx < 3; ++kx) {
                    const float4* wp =
                        (const float4*)&swT[(ci * 9 + ky * 3 + kx) * 16 + oc * 8];
                    float4 w0 = wp[0], w1 = wp[1];
#pragma unroll
                    for (int pq = 0; pq < 4; ++pq) {
                        float xv = in[ci][(pq >> 1) + ky][(pq & 1) + kx];
                        acc[pq][0] = fmaf(w0.x, xv, acc[pq][0]);
                        acc[pq][1] = fmaf(w0.y, xv, acc[pq][1]);
                        acc[pq][2] = fmaf(w0.z, xv, acc[pq][2]);
                        acc[pq][3] = fmaf(w0.w, xv, acc[pq][3]);
                        acc[pq][4] = fmaf(w1.x, xv, acc[pq][4]);
                        acc[pq][5] = fmaf(w1.y, xv, acc[pq][5]);
                        acc[pq][6] = fmaf(w1.z, xv, acc[pq][6]);
                        acc[pq][7] = fmaf(w1.w, xv, acc[pq][7]);
                    }
                }
#pragma unroll
        for (int oo = 0; oo < 8; ++oo) {
            float m = fmaxf(fmaxf(acc[0][oo], acc[1][oo]),
                            fmaxf(acc[2][oo], acc[3][oo]));
            int ch = og * 16 + oc * 8 + oo;
            c[ch * 262144 + pix] = m;
            float v = fmaxf(m, __shfl_xor(m, 1, 64));
            v = fmaxf(v, __shfl_xor(v, 16, 64));
            if (pwrite) p[ch * 65536 + ppix] = v;
        }
    }
}

// pixel_match at 512 res + fused maxpool2 -> feat ch0..19.
// One thread per src px; all 32 ch in-thread; pool via shfl 2x2.
__global__ __launch_bounds__(256, 4) void pm512_pool_kernel(
    const float* __restrict__ c1, const float* __restrict__ c2,
    float* __restrict__ feat) {
    int tx = threadIdx.x, ty = threadIdx.y;
    int sw = blockIdx.x * 16 + tx;
    int sh = blockIdx.y * 16 + ty;
    float d[20];
    bool interior = (sh >= 1 && sh <= 510 && sw >= 1 && sw <= 510);
    if (interior) {
        float a1[9], a2[9];
#pragma unroll
        for (int k = 0; k < 9; ++k) { a1[k] = 0.f; a2[k] = 0.f; }
        const float* b1 = c1 + sh * 512 + sw;
        const float* b2 = c2 + sh * 512 + sw;
        for (int ch = 0; ch < 32; ++ch) {
            float y1 = b1[0], y2 = b2[0];
#pragma unroll
            for (int dh = -1; dh <= 1; ++dh)
#pragma unroll
                for (int dw = -1; dw <= 1; ++dw) {
                    int k = (dh + 1) * 3 + (dw + 1);
                    float n1 = b1[dh * 512 + dw];
                    float n2 = b2[dh * 512 + dw];
                    float t1 = n1 - y2, t2 = n2 - y1;
                    a1[k] = fmaf(t1, t1, a1[k]);
                    a2[k] = fmaf(t2, t2, a2[k]);
                }
            b1 += 262144;
            b2 += 262144;
        }
        float s1 = 0.f, s2 = 0.f;
#pragma unroll
        for (int k = 0; k < 9; ++k) {
            a1[k] = 1.0f / sqrtf(a1[k] + 0.01f);
            a2[k] = 1.0f / sqrtf(a2[k] + 0.01f);
            s1 += a1[k];
            s2 += a2[k];
        }
        float i1 = 1.0f / s1, i2 = 1.0f / s2;
#pragma unroll
        for (int k = 0; k < 9; ++k) {
            d[k] = a1[k] * i1;
            d[9 + k] = a2[k] * i2;
        }
    } else {
#pragma unroll
        for (int k = 0; k < 18; ++k) d[k] = 1.0f / 9.0f;
    }
    d[18] = 2.0f * sh / 511.0f - 1.0f;
    d[19] = 2.0f * sw / 511.0f - 1.0f;
#pragma unroll
    for (int k = 0; k < 20; ++k) {
        float v = d[k];
        v = fmaxf(v, __shfl_xor(v, 1, 64));
        v = fmaxf(v, __shfl_xor(v, 16, 64));
        d[k] = v;
    }
    if (((tx | ty) & 1) == 0) {
        int pix = (sh >> 1) * 256 + (sw >> 1);
#pragma unroll
        for (int k = 0; k < 20; ++k) feat[k * 65536 + pix] = d[k];
    }
}

// pixel_match at 256 res -> feat ch20..39. Channel-split 4 ways + LDS reduce.
__global__ __launch_bounds__(256) void pm256_kernel(
    const float* __restrict__ p1, const float* __restrict__ p2,
    float* __restrict__ feat) {
    __shared__ float part[4][64][19];
    int lane = threadIdx.x, grp = threadIdx.y;
    int w = blockIdx.x * 8 + (lane & 7);
    int h = blockIdx.y * 8 + (lane >> 3);
    bool interior = (h >= 1 && h <= 254 && w >= 1 && w <= 254);
    float a1[9], a2[9];
#pragma unroll
    for (int k = 0; k < 9; ++k) { a1[k] = 0.f; a2[k] = 0.f; }
    if (interior) {
        int ctr = h * 256 + w;
        for (int c = grp * 8; c < grp * 8 + 8; ++c) {
            const float* b1 = p1 + c * 65536;
            const float* b2 = p2 + c * 65536;
            float y1 = b1[ctr], y2 = b2[ctr];
#pragma unroll
            for (int dh = 0; dh < 3; ++dh)
#pragma unroll
                for (int dw = 0; dw < 3; ++dw) {
                    int off = (h + dh - 1) * 256 + (w + dw - 1);
                    float n1 = b1[off], n2 = b2[off];
                    float t1 = n1 - y2, t2 = n2 - y1;
                    a1[dh * 3 + dw] = fmaf(t1, t1, a1[dh * 3 + dw]);
                    a2[dh * 3 + dw] = fmaf(t2, t2, a2[dh * 3 + dw]);
                }
        }
    }
#pragma unroll
    for (int k = 0; k < 9; ++k) {
        part[grp][lane][k] = a1[k];
        part[grp][lane][k + 9] = a2[k];
    }
    __syncthreads();
    if (grp == 0) {
        int pix = h * 256 + w;
        if (interior) {
            float d1[9], d2[9];
            float s1 = 0.f, s2 = 0.f;
#pragma unroll
            for (int k = 0; k < 9; ++k) {
                float t1 = part[0][lane][k] + part[1][lane][k] +
                           part[2][lane][k] + part[3][lane][k];
                float t2 = part[0][lane][k + 9] + part[1][lane][k + 9] +
                           part[2][lane][k + 9] + part[3][lane][k + 9];
                d1[k] = 1.0f / sqrtf(t1 + 0.01f);
                d2[k] = 1.0f / sqrtf(t2 + 0.01f);
                s1 += d1[k];
                s2 += d2[k];
            }
            float i1 = 1.0f / s1, i2 = 1.0f / s2;
#pragma unroll
            for (int k = 0; k < 9; ++k) {
                feat[(20 + k) * 65536 + pix] = d1[k] * i1;
                feat[(29 + k) * 65536 + pix] = d2[k] * i2;
            }
        } else {
#pragma unroll
            for (int k = 0; k < 18; ++k)
                feat[(20 + k) * 65536 + pix] = 1.0f / 9.0f;
        }
        feat[38 * 65536 + pix] = 2.0f * h / 255.0f - 1.0f;
        feat[39 * 65536 + pix] = 2.0f * w / 255.0f - 1.0f;
    }
}

// Dense conv5x5 partial sums: grid (8,8,8); z = ci group (4 channels).
__global__ __launch_bounds__(256) void dense_part_kernel(
    const float* __restrict__ p1, const float* __restrict__ p2,
    const float* __restrict__ dw, float* __restrict__ part) {
    __shared__ float sdiff[4 * 1296];   // [4][36][36]
    __shared__ float sw[4 * 8 * 28];    // [ci][o][28]
    int tx = threadIdx.x, ty = threadIdx.y;
    int tid = ty * 16 + tx;
    int bz = blockIdx.z;
    int h0 = blockIdx.y * 32, w0 = blockIdx.x * 32;
    for (int idx = tid; idx < 4 * 1296; idx += 256) {
        int ci = idx / 1296, r = idx % 1296;
        int yy = r / 36, xx = r % 36;
        int gy = h0 + yy - 2, gx = w0 + xx - 2;
        float v = 0.f;
        if (gy >= 0 && gy < 256 && gx >= 0 && gx < 256) {
            int g = (bz * 4 + ci) * 65536 + gy * 256 + gx;
            v = p1[g] - p2[g];
        }
        sdiff[idx] = v;
    }
    for (int idx = tid; idx < 4 * 8 * 28; idx += 256) {
        int ci = idx / 224, r = idx % 224;
        int o = r / 28, k = r % 28;
        sw[idx] = (k < 25) ? dw[o * 800 + (bz * 4 + ci) * 25 + k] : 0.f;
    }
    __syncthreads();
    float acc[4][8];
#pragma unroll
    for (int pq = 0; pq < 4; ++pq)
#pragma unroll
        for (int o = 0; o < 8; ++o) acc[pq][o] = 0.f;
    for (int ci = 0; ci < 4; ++ci) {
        float patch[6][6];
#pragma unroll
        for (int yy = 0; yy < 6; ++yy) {
            const float* rowp = &sdiff[ci * 1296 + (2 * ty + yy) * 36 + 2 * tx];
#pragma unroll
            for (int cpair = 0; cpair < 3; ++cpair) {
                float2 lp = *(const float2*)&rowp[2 * cpair];
                patch[yy][2 * cpair] = lp.x;
                patch[yy][2 * cpair + 1] = lp.y;
            }
        }
#pragma unroll
        for (int o = 0; o < 8; ++o) {
            float wreg[28];
            const float4* wp = (const float4*)&sw[(ci * 8 + o) * 28];
#pragma unroll
            for (int q = 0; q < 7; ++q) {
                float4 wv = wp[q];
                wreg[4 * q] = wv.x;
                wreg[4 * q + 1] = wv.y;
                wreg[4 * q + 2] = wv.z;
                wreg[4 * q + 3] = wv.w;
            }
#pragma unroll
            for (int ky = 0; ky < 5; ++ky)
#pragma unroll
                for (int kx = 0; kx < 5; ++kx) {
                    float wv = wreg[ky * 5 + kx];
#pragma unroll
                    for (int pq = 0; pq < 4; ++pq)
                        acc[pq][o] = fmaf(
                            wv, patch[ky + (pq >> 1)][kx + (pq & 1)], acc[pq][o]);
                }
        }
    }
#pragma unroll
    for (int pq = 0; pq < 4; ++pq) {
        int h = h0 + 2 * ty + (pq >> 1), w = w0 + 2 * tx + (pq & 1);
        int pix = h * 256 + w;
#pragma unroll
        for (int o = 0; o < 8; ++o)
            part[bz * 524288 + o * 65536 + pix] = acc[pq][o];
    }
}

// Reduce 8 partials + bias + leaky_relu -> feat ch40..47.
__global__ __launch_bounds__(256) void dense_reduce_kernel(
    const float* __restrict__ part, const float* __restrict__ db,
    float* __restrict__ feat) {
    int idx = blockIdx.x * 256 + threadIdx.x;
    int o = idx >> 16;
    float s = db[o];
#pragma unroll
    for (int z = 0; z < 8; ++z) s += part[z * 524288 + idx];
    float v = (s >= 0.f) ? s : 0.01f * s;
    feat[40 * 65536 + idx] = v;
}

// 1x1 conv 48->64, o-split 2 ways: grid (256,2), 32 outputs each.
__global__ __launch_bounds__(256) void f1_kernel(
    const float* __restrict__ feat, const float* __restrict__ f1w,
    const float* __restrict__ f1b, float* __restrict__ out) {
    __shared__ float sw[1536];
    __shared__ float sb[32];
    int og = blockIdx.y;
    int tid = threadIdx.x;
    for (int i = tid; i < 1536; i += 256) sw[i] = f1w[og * 1536 + i];
    if (tid < 32) sb[tid] = f1b[og * 32 + tid];
    __syncthreads();
    int pix = blockIdx.x * 256 + tid;
    float f[48];
#pragma unroll
    for (int c = 0; c < 48; ++c) f[c] = feat[c * 65536 + pix];
#pragma unroll
    for (int o = 0; o < 32; ++o) {
        float a = sb[o];
        const float4* wv = (const float4*)&sw[o * 48];
#pragma unroll
        for (int c4 = 0; c4 < 12; ++c4) {
            float4 ww = wv[c4];
            a = fmaf(ww.x, f[c4 * 4], a);
            a = fmaf(ww.y, f[c4 * 4 + 1], a);
            a = fmaf(ww.z, f[c4 * 4 + 2], a);
            a = fmaf(ww.w, f[c4 * 4 + 3], a);
        }
        out[(og * 32 + o) * 65536 + pix] = a;
    }
}

// adaptive_max_pool3: one block per (channel, i, j); overlapping regions.
__global__ __launch_bounds__(256) void pool3_kernel(
    const float* __restrict__ f1out, float* __restrict__ pooled) {
    int b = blockIdx.x;  // 64*9
    int c = b / 9, ij = b % 9, i = ij / 3, j = ij % 3;
    int hs = (i * 256) / 3, he = ((i + 1) * 256 + 2) / 3;
    int ws = (j * 256) / 3, we = ((j + 1) * 256 + 2) / 3;
    const float* src = f1out + c * 65536;
    int nh = he - hs, nw = we - ws, tot = nh * nw;
    float m = -INFINITY;
    for (int t = threadIdx.x; t < tot; t += 256) {
        int r = t / nw, q = t - r * nw;
        m = fmaxf(m, src[(hs + r) * 256 + (ws + q)]);
    }
    for (int off = 32; off > 0; off >>= 1) m = fmaxf(m, __shfl_down(m, off, 64));
    __shared__ float red[4];
    if ((threadIdx.x & 63) == 0) red[threadIdx.x >> 6] = m;
    __syncthreads();
    if (threadIdx.x == 0)
        pooled[b] = fmaxf(fmaxf(red[0], red[1]), fmaxf(red[2], red[3]));
}

// f2 conv (64,3,3)->128, L2-normalize, f3 matmul -> 6, assemble 3x3 output.
__global__ __launch_bounds__(128) void final_kernel(
    const float* __restrict__ pooled, const float* __restrict__ f2w,
    const float* __restrict__ f2b, const float* __restrict__ f3w,
    const float* __restrict__ f3b, float* __restrict__ out) {
    __shared__ float xn[128];
    __shared__ float red[2];
    __shared__ float ov[6];
    int t = threadIdx.x;
    float a = f2b[t];
    for (int c = 0; c < 64; ++c)
#pragma unroll
        for (int k = 0; k < 9; ++k)
            a = fmaf(f2w[t * 576 + c * 9 + k], pooled[c * 9 + k], a);
    float sq = a * a;
    for (int off = 32; off > 0; off >>= 1) sq += __shfl_down(sq, off, 64);
    if ((t & 63) == 0) red[t >> 6] = sq;
    __syncthreads();
    float tmp = red[0] + red[1] + 0.001f;
    float scale = 1.0f / sqrtf(tmp);
    xn[t] = a * scale;
    __syncthreads();
    if (t < 6) {
        float o = f3b[t];
        for (int k = 0; k < 128; ++k) o = fmaf(f3w[t * 128 + k], xn[k], o);
        ov[t] = o;
    }
    __syncthreads();
    if (t < 9) {
        int r = t / 3, cc = t % 3;
        float v = 0.f;
        if (r < 2) {
            float x = ov[r * 3 + cc];
            float cl = fminf(fmaxf(x, -0.11f), 0.11f);
            v = cl + 0.01f * x;
        }
        if (r == cc) v += 1.0f;
        out[t] = v;
    }
}

extern "C" void kernel_launch(void* const* d_in, const int* in_sizes, int n_in,
                              void* d_out, int out_size, void* d_ws,
                              size_t ws_size, hipStream_t stream) {
    const float* x1 = (const float*)d_in[0];
    const float* x2 = (const float*)d_in[1];
    const float* enc_w = (const float*)d_in[2];
    const float* enc_b = (const float*)d_in[3];
    const float* embed_w = (const float*)d_in[4];
    const float* embed_b = (const float*)d_in[5];
    const float* dense_w = (const float*)d_in[6];
    const float* dense_b = (const float*)d_in[7];
    const float* f1_w = (const float*)d_in[8];
    const float* f1_b = (const float*)d_in[9];
    const float* f2_w = (const float*)d_in[10];
    const float* f2_b = (const float*)d_in[11];
    const float* f3_w = (const float*)d_in[12];
    const float* f3_b = (const float*)d_in[13];

    float* ws = (float*)d_ws;
    float* weff_t = ws;                 // 864
    float* beff = ws + 864;             // 32
    float* c1 = ws + 1024;              // 32*512*512 = 8388608
    float* c2 = c1 + 8388608;
    float* p1 = c2 + 8388608;           // 32*256*256 = 2097152
    float* p2 = p1 + 2097152;
    float* feat = p2 + 2097152;         // 48*256*256 = 3145728
    float* pooled = feat + 3145728;     // 576
    float* f1o = c1;                    // alias: c1 dead after pm512
    float* part = c2;                   // alias: c2 dead after pm512 (4.2M)

    fuse_weights_kernel<<<1, 256, 0, stream>>>(enc_w, enc_b, embed_w, embed_b,
                                               weff_t, beff);
    coding_kernel<<<dim3(32, 32, 4), dim3(16, 16), 0, stream>>>(
        x1, x2, weff_t, beff, c1, c2, p1, p2);
    pm512_pool_kernel<<<dim3(32, 32), dim3(16, 16), 0, stream>>>(c1, c2, feat);
    pm256_kernel<<<dim3(32, 32), dim3(64, 4), 0, stream>>>(p1, p2, feat);
    dense_part_kernel<<<dim3(8, 8, 8), dim3(16, 16), 0, stream>>>(
        p1, p2, dense_w, part);
    dense_reduce_kernel<<<2048, 256, 0, stream>>>(part, dense_b, feat);
    f1_kernel<<<dim3(256, 2), 256, 0, stream>>>(feat, f1_w, f1_b, f1o);
    pool3_kernel<<<576, 256, 0, stream>>>(f1o, pooled);
    final_kernel<<<1, 128, 0, stream>>>(pooled, f2_w, f2_b, f3_w, f3_b,
                                        (float*)d_out);
}

// Round 6
// 235.455 us; speedup vs baseline: 7.1582x; 7.1582x over previous
//
#include <hip/hip_runtime.h>
#include <math.h>

// ---------------------------------------------------------------------------
// MyNet: two 1024x1024x3 images -> 3x3 matrix.
// R6: coding restructured for low register pressure WITHOUT forced launch
//     bounds (R5's (256,4) forced 64 VGPR -> 6 GB of spill traffic).
//     One thread per src-pixel-pair; oc(x4,unroll1) x ci(unroll1) loops
//     reload a 12-float patch from L1 instead of 48-reg live patch.
//     Both maxpools fused via shfl_xor. pm512's forced bound removed.
// ---------------------------------------------------------------------------

__global__ void fuse_weights_kernel(const float* __restrict__ enc_w,
                                    const float* __restrict__ enc_b,
                                    const float* __restrict__ embed_w,
                                    const float* __restrict__ embed_b,
                                    float* __restrict__ weff_t,
                                    float* __restrict__ beff) {
    int t = threadIdx.x;
    for (int idx = t; idx < 27 * 32; idx += blockDim.x) {
        int r = idx >> 5, o = idx & 31;
        float s = 0.f;
        for (int k = 0; k < 24; ++k) s += embed_w[o * 24 + k] * enc_w[k * 27 + r];
        weff_t[idx] = s;
    }
    if (t < 32) {
        float s = embed_b[t];
        for (int k = 0; k < 24; ++k) s += embed_w[t * 24 + k] * enc_b[k];
        beff[t] = s;
    }
}

// Fused enc+embed 3x3 conv (3->32) at 1024 res + maxpool2 -> c (512^2)
// + maxpool2 -> p (256^2), pools via shfl.
// Thread (tx,ty): conv at row Y=by*16+ty, cols X0=2*(bx*16+tx), X0+1.
// Wave = 4 ty-rows: xor16 = ty bit0 (512-pool vert), xor1 = tx bit0,
// xor32 = ty bit1 (256-pool).
__global__ __launch_bounds__(256) void coding_kernel(
    const float* __restrict__ x1, const float* __restrict__ x2,
    const float* __restrict__ weff_t, const float* __restrict__ beff,
    float* __restrict__ c1, float* __restrict__ c2,
    float* __restrict__ p1, float* __restrict__ p2) {
    __shared__ float swT[864];  // [27][32]
    __shared__ float sb[32];
    int tx = threadIdx.x, ty = threadIdx.y;
    int tid = ty * 16 + tx;
    for (int i = tid; i < 864; i += 256) swT[i] = weff_t[i];
    if (tid < 32) sb[tid] = beff[tid];
    __syncthreads();
    int img = blockIdx.z;
    const float* x = img ? x2 : x1;
    float* c = img ? c2 : c1;
    float* p = img ? p2 : p1;
    int Y = blockIdx.y * 16 + ty;   // src row 0..1023
    int cx = blockIdx.x * 16 + tx;  // c col 0..511
    int X0 = 2 * cx;
    bool interior = (blockIdx.y > 0 && blockIdx.y < 63 &&
                     blockIdx.x > 0 && blockIdx.x < 31);
    int cpix = (Y >> 1) * 512 + cx;
    int ppix = (Y >> 2) * 256 + (cx >> 1);
    bool cwrite = ((ty & 1) == 0);
    bool pwrite = ((ty & 3) == 0) && ((tx & 1) == 0);
#pragma unroll 1
    for (int oc = 0; oc < 4; ++oc) {
        float acc0[8], acc1[8];
#pragma unroll
        for (int o = 0; o < 8; ++o) {
            acc0[o] = sb[oc * 8 + o];
            acc1[o] = acc0[o];
        }
#pragma unroll 1
        for (int ci = 0; ci < 3; ++ci) {
            float in[3][4];
            const float* xc = x + ci * 1048576;
            if (interior) {
#pragma unroll
                for (int r = 0; r < 3; ++r) {
                    const float* row = xc + (Y - 1 + r) * 1024 + X0 - 1;
#pragma unroll
                    for (int q = 0; q < 4; ++q) in[r][q] = row[q];
                }
            } else {
#pragma unroll
                for (int r = 0; r < 3; ++r)
#pragma unroll
                    for (int q = 0; q < 4; ++q) {
                        int gy = Y - 1 + r, gx = X0 - 1 + q;
                        in[r][q] = (gy >= 0 && gy < 1024 && gx >= 0 && gx < 1024)
                                       ? xc[gy * 1024 + gx]
                                       : 0.f;
                    }
            }
#pragma unroll
            for (int ky = 0; ky < 3; ++ky)
#pragma unroll
                for (int kx = 0; kx < 3; ++kx) {
                    const float4* wp =
                        (const float4*)&swT[(ci * 9 + ky * 3 + kx) * 32 + oc * 8];
                    float4 w0 = wp[0], w1 = wp[1];
                    float xa = in[ky][kx];      // position X0
                    float xb = in[ky][kx + 1];  // position X0+1
                    acc0[0] = fmaf(w0.x, xa, acc0[0]);
                    acc1[0] = fmaf(w0.x, xb, acc1[0]);
                    acc0[1] = fmaf(w0.y, xa, acc0[1]);
                    acc1[1] = fmaf(w0.y, xb, acc1[1]);
                    acc0[2] = fmaf(w0.z, xa, acc0[2]);
                    acc1[2] = fmaf(w0.z, xb, acc1[2]);
                    acc0[3] = fmaf(w0.w, xa, acc0[3]);
                    acc1[3] = fmaf(w0.w, xb, acc1[3]);
                    acc0[4] = fmaf(w1.x, xa, acc0[4]);
                    acc1[4] = fmaf(w1.x, xb, acc1[4]);
                    acc0[5] = fmaf(w1.y, xa, acc0[5]);
                    acc1[5] = fmaf(w1.y, xb, acc1[5]);
                    acc0[6] = fmaf(w1.z, xa, acc0[6]);
                    acc1[6] = fmaf(w1.z, xb, acc1[6]);
                    acc0[7] = fmaf(w1.w, xa, acc0[7]);
                    acc1[7] = fmaf(w1.w, xb, acc1[7]);
                }
        }
#pragma unroll
        for (int o = 0; o < 8; ++o) {
            float m = fmaxf(acc0[o], acc1[o]);         // horizontal pair
            m = fmaxf(m, __shfl_xor(m, 16, 64));       // vertical pair -> c
            int ch = oc * 8 + o;
            if (cwrite) c[ch * 262144 + cpix] = m;
            float v = fmaxf(m, __shfl_xor(m, 1, 64));  // c-col pair
            v = fmaxf(v, __shfl_xor(v, 32, 64));       // c-row pair -> p
            if (pwrite) p[ch * 65536 + ppix] = v;
        }
    }
}

// pixel_match at 512 res + fused maxpool2 -> feat ch0..19.
// One thread per src px; all 32 ch in-thread; pool via shfl 2x2.
__global__ __launch_bounds__(256) void pm512_pool_kernel(
    const float* __restrict__ c1, const float* __restrict__ c2,
    float* __restrict__ feat) {
    int tx = threadIdx.x, ty = threadIdx.y;
    int sw = blockIdx.x * 16 + tx;
    int sh = blockIdx.y * 16 + ty;
    float d[20];
    bool interior = (sh >= 1 && sh <= 510 && sw >= 1 && sw <= 510);
    if (interior) {
        float a1[9], a2[9];
#pragma unroll
        for (int k = 0; k < 9; ++k) { a1[k] = 0.f; a2[k] = 0.f; }
        const float* b1 = c1 + sh * 512 + sw;
        const float* b2 = c2 + sh * 512 + sw;
        for (int ch = 0; ch < 32; ++ch) {
            float y1 = b1[0], y2 = b2[0];
#pragma unroll
            for (int dh = -1; dh <= 1; ++dh)
#pragma unroll
                for (int dw = -1; dw <= 1; ++dw) {
                    int k = (dh + 1) * 3 + (dw + 1);
                    float n1 = b1[dh * 512 + dw];
                    float n2 = b2[dh * 512 + dw];
                    float t1 = n1 - y2, t2 = n2 - y1;
                    a1[k] = fmaf(t1, t1, a1[k]);
                    a2[k] = fmaf(t2, t2, a2[k]);
                }
            b1 += 262144;
            b2 += 262144;
        }
        float s1 = 0.f, s2 = 0.f;
#pragma unroll
        for (int k = 0; k < 9; ++k) {
            a1[k] = 1.0f / sqrtf(a1[k] + 0.01f);
            a2[k] = 1.0f / sqrtf(a2[k] + 0.01f);
            s1 += a1[k];
            s2 += a2[k];
        }
        float i1 = 1.0f / s1, i2 = 1.0f / s2;
#pragma unroll
        for (int k = 0; k < 9; ++k) {
            d[k] = a1[k] * i1;
            d[9 + k] = a2[k] * i2;
        }
    } else {
#pragma unroll
        for (int k = 0; k < 18; ++k) d[k] = 1.0f / 9.0f;
    }
    d[18] = 2.0f * sh / 511.0f - 1.0f;
    d[19] = 2.0f * sw / 511.0f - 1.0f;
#pragma unroll
    for (int k = 0; k < 20; ++k) {
        float v = d[k];
        v = fmaxf(v, __shfl_xor(v, 1, 64));
        v = fmaxf(v, __shfl_xor(v, 16, 64));
        d[k] = v;
    }
    if (((tx | ty) & 1) == 0) {
        int pix = (sh >> 1) * 256 + (sw >> 1);
#pragma unroll
        for (int k = 0; k < 20; ++k) feat[k * 65536 + pix] = d[k];
    }
}

// pixel_match at 256 res -> feat ch20..39. Channel-split 4 ways + LDS reduce.
__global__ __launch_bounds__(256) void pm256_kernel(
    const float* __restrict__ p1, const float* __restrict__ p2,
    float* __restrict__ feat) {
    __shared__ float part[4][64][19];
    int lane = threadIdx.x, grp = threadIdx.y;
    int w = blockIdx.x * 8 + (lane & 7);
    int h = blockIdx.y * 8 + (lane >> 3);
    bool interior = (h >= 1 && h <= 254 && w >= 1 && w <= 254);
    float a1[9], a2[9];
#pragma unroll
    for (int k = 0; k < 9; ++k) { a1[k] = 0.f; a2[k] = 0.f; }
    if (interior) {
        int ctr = h * 256 + w;
        for (int c = grp * 8; c < grp * 8 + 8; ++c) {
            const float* b1 = p1 + c * 65536;
            const float* b2 = p2 + c * 65536;
            float y1 = b1[ctr], y2 = b2[ctr];
#pragma unroll
            for (int dh = 0; dh < 3; ++dh)
#pragma unroll
                for (int dw = 0; dw < 3; ++dw) {
                    int off = (h + dh - 1) * 256 + (w + dw - 1);
                    float n1 = b1[off], n2 = b2[off];
                    float t1 = n1 - y2, t2 = n2 - y1;
                    a1[dh * 3 + dw] = fmaf(t1, t1, a1[dh * 3 + dw]);
                    a2[dh * 3 + dw] = fmaf(t2, t2, a2[dh * 3 + dw]);
                }
        }
    }
#pragma unroll
    for (int k = 0; k < 9; ++k) {
        part[grp][lane][k] = a1[k];
        part[grp][lane][k + 9] = a2[k];
    }
    __syncthreads();
    if (grp == 0) {
        int pix = h * 256 + w;
        if (interior) {
            float d1[9], d2[9];
            float s1 = 0.f, s2 = 0.f;
#pragma unroll
            for (int k = 0; k < 9; ++k) {
                float t1 = part[0][lane][k] + part[1][lane][k] +
                           part[2][lane][k] + part[3][lane][k];
                float t2 = part[0][lane][k + 9] + part[1][lane][k + 9] +
                           part[2][lane][k + 9] + part[3][lane][k + 9];
                d1[k] = 1.0f / sqrtf(t1 + 0.01f);
                d2[k] = 1.0f / sqrtf(t2 + 0.01f);
                s1 += d1[k];
                s2 += d2[k];
            }
            float i1 = 1.0f / s1, i2 = 1.0f / s2;
#pragma unroll
            for (int k = 0; k < 9; ++k) {
                feat[(20 + k) * 65536 + pix] = d1[k] * i1;
                feat[(29 + k) * 65536 + pix] = d2[k] * i2;
            }
        } else {
#pragma unroll
            for (int k = 0; k < 18; ++k)
                feat[(20 + k) * 65536 + pix] = 1.0f / 9.0f;
        }
        feat[38 * 65536 + pix] = 2.0f * h / 255.0f - 1.0f;
        feat[39 * 65536 + pix] = 2.0f * w / 255.0f - 1.0f;
    }
}

// Dense conv5x5 partial sums: grid (8,8,8); z = ci group (4 channels).
__global__ __launch_bounds__(256) void dense_part_kernel(
    const float* __restrict__ p1, const float* __restrict__ p2,
    const float* __restrict__ dw, float* __restrict__ part) {
    __shared__ float sdiff[4 * 1296];   // [4][36][36]
    __shared__ float sw[4 * 8 * 28];    // [ci][o][28]
    int tx = threadIdx.x, ty = threadIdx.y;
    int tid = ty * 16 + tx;
    int bz = blockIdx.z;
    int h0 = blockIdx.y * 32, w0 = blockIdx.x * 32;
    for (int idx = tid; idx < 4 * 1296; idx += 256) {
        int ci = idx / 1296, r = idx % 1296;
        int yy = r / 36, xx = r % 36;
        int gy = h0 + yy - 2, gx = w0 + xx - 2;
        float v = 0.f;
        if (gy >= 0 && gy < 256 && gx >= 0 && gx < 256) {
            int g = (bz * 4 + ci) * 65536 + gy * 256 + gx;
            v = p1[g] - p2[g];
        }
        sdiff[idx] = v;
    }
    for (int idx = tid; idx < 4 * 8 * 28; idx += 256) {
        int ci = idx / 224, r = idx % 224;
        int o = r / 28, k = r % 28;
        sw[idx] = (k < 25) ? dw[o * 800 + (bz * 4 + ci) * 25 + k] : 0.f;
    }
    __syncthreads();
    float acc[4][8];
#pragma unroll
    for (int pq = 0; pq < 4; ++pq)
#pragma unroll
        for (int o = 0; o < 8; ++o) acc[pq][o] = 0.f;
    for (int ci = 0; ci < 4; ++ci) {
        float patch[6][6];
#pragma unroll
        for (int yy = 0; yy < 6; ++yy) {
            const float* rowp = &sdiff[ci * 1296 + (2 * ty + yy) * 36 + 2 * tx];
#pragma unroll
            for (int cpair = 0; cpair < 3; ++cpair) {
                float2 lp = *(const float2*)&rowp[2 * cpair];
                patch[yy][2 * cpair] = lp.x;
                patch[yy][2 * cpair + 1] = lp.y;
            }
        }
#pragma unroll
        for (int o = 0; o < 8; ++o) {
            float wreg[28];
            const float4* wp = (const float4*)&sw[(ci * 8 + o) * 28];
#pragma unroll
            for (int q = 0; q < 7; ++q) {
                float4 wv = wp[q];
                wreg[4 * q] = wv.x;
                wreg[4 * q + 1] = wv.y;
                wreg[4 * q + 2] = wv.z;
                wreg[4 * q + 3] = wv.w;
            }
#pragma unroll
            for (int ky = 0; ky < 5; ++ky)
#pragma unroll
                for (int kx = 0; kx < 5; ++kx) {
                    float wv = wreg[ky * 5 + kx];
#pragma unroll
                    for (int pq = 0; pq < 4; ++pq)
                        acc[pq][o] = fmaf(
                            wv, patch[ky + (pq >> 1)][kx + (pq & 1)], acc[pq][o]);
                }
        }
    }
#pragma unroll
    for (int pq = 0; pq < 4; ++pq) {
        int h = h0 + 2 * ty + (pq >> 1), w = w0 + 2 * tx + (pq & 1);
        int pix = h * 256 + w;
#pragma unroll
        for (int o = 0; o < 8; ++o)
            part[bz * 524288 + o * 65536 + pix] = acc[pq][o];
    }
}

// Reduce 8 partials + bias + leaky_relu -> feat ch40..47.
__global__ __launch_bounds__(256) void dense_reduce_kernel(
    const float* __restrict__ part, const float* __restrict__ db,
    float* __restrict__ feat) {
    int idx = blockIdx.x * 256 + threadIdx.x;
    int o = idx >> 16;
    float s = db[o];
#pragma unroll
    for (int z = 0; z < 8; ++z) s += part[z * 524288 + idx];
    float v = (s >= 0.f) ? s : 0.01f * s;
    feat[40 * 65536 + idx] = v;
}

// 1x1 conv 48->64, o-split 2 ways: grid (256,2), 32 outputs each.
__global__ __launch_bounds__(256) void f1_kernel(
    const float* __restrict__ feat, const float* __restrict__ f1w,
    const float* __restrict__ f1b, float* __restrict__ out) {
    __shared__ float sw[1536];
    __shared__ float sb[32];
    int og = blockIdx.y;
    int tid = threadIdx.x;
    for (int i = tid; i < 1536; i += 256) sw[i] = f1w[og * 1536 + i];
    if (tid < 32) sb[tid] = f1b[og * 32 + tid];
    __syncthreads();
    int pix = blockIdx.x * 256 + tid;
    float f[48];
#pragma unroll
    for (int c = 0; c < 48; ++c) f[c] = feat[c * 65536 + pix];
#pragma unroll
    for (int o = 0; o < 32; ++o) {
        float a = sb[o];
        const float4* wv = (const float4*)&sw[o * 48];
#pragma unroll
        for (int c4 = 0; c4 < 12; ++c4) {
            float4 ww = wv[c4];
            a = fmaf(ww.x, f[c4 * 4], a);
            a = fmaf(ww.y, f[c4 * 4 + 1], a);
            a = fmaf(ww.z, f[c4 * 4 + 2], a);
            a = fmaf(ww.w, f[c4 * 4 + 3], a);
        }
        out[(og * 32 + o) * 65536 + pix] = a;
    }
}

// adaptive_max_pool3: one block per (channel, i, j); overlapping regions.
__global__ __launch_bounds__(256) void pool3_kernel(
    const float* __restrict__ f1out, float* __restrict__ pooled) {
    int b = blockIdx.x;  // 64*9
    int c = b / 9, ij = b % 9, i = ij / 3, j = ij % 3;
    int hs = (i * 256) / 3, he = ((i + 1) * 256 + 2) / 3;
    int ws = (j * 256) / 3, we = ((j + 1) * 256 + 2) / 3;
    const float* src = f1out + c * 65536;
    int nh = he - hs, nw = we - ws, tot = nh * nw;
    float m = -INFINITY;
    for (int t = threadIdx.x; t < tot; t += 256) {
        int r = t / nw, q = t - r * nw;
        m = fmaxf(m, src[(hs + r) * 256 + (ws + q)]);
    }
    for (int off = 32; off > 0; off >>= 1) m = fmaxf(m, __shfl_down(m, off, 64));
    __shared__ float red[4];
    if ((threadIdx.x & 63) == 0) red[threadIdx.x >> 6] = m;
    __syncthreads();
    if (threadIdx.x == 0)
        pooled[b] = fmaxf(fmaxf(red[0], red[1]), fmaxf(red[2], red[3]));
}

// f2 conv (64,3,3)->128, L2-normalize, f3 matmul -> 6, assemble 3x3 output.
__global__ __launch_bounds__(128) void final_kernel(
    const float* __restrict__ pooled, const float* __restrict__ f2w,
    const float* __restrict__ f2b, const float* __restrict__ f3w,
    const float* __restrict__ f3b, float* __restrict__ out) {
    __shared__ float xn[128];
    __shared__ float red[2];
    __shared__ float ov[6];
    int t = threadIdx.x;
    float a = f2b[t];
    for (int c = 0; c < 64; ++c)
#pragma unroll
        for (int k = 0; k < 9; ++k)
            a = fmaf(f2w[t * 576 + c * 9 + k], pooled[c * 9 + k], a);
    float sq = a * a;
    for (int off = 32; off > 0; off >>= 1) sq += __shfl_down(sq, off, 64);
    if ((t & 63) == 0) red[t >> 6] = sq;
    __syncthreads();
    float tmp = red[0] + red[1] + 0.001f;
    float scale = 1.0f / sqrtf(tmp);
    xn[t] = a * scale;
    __syncthreads();
    if (t < 6) {
        float o = f3b[t];
        for (int k = 0; k < 128; ++k) o = fmaf(f3w[t * 128 + k], xn[k], o);
        ov[t] = o;
    }
    __syncthreads();
    if (t < 9) {
        int r = t / 3, cc = t % 3;
        float v = 0.f;
        if (r < 2) {
            float x = ov[r * 3 + cc];
            float cl = fminf(fmaxf(x, -0.11f), 0.11f);
            v = cl + 0.01f * x;
        }
        if (r == cc) v += 1.0f;
        out[t] = v;
    }
}

extern "C" void kernel_launch(void* const* d_in, const int* in_sizes, int n_in,
                              void* d_out, int out_size, void* d_ws,
                              size_t ws_size, hipStream_t stream) {
    const float* x1 = (const float*)d_in[0];
    const float* x2 = (const float*)d_in[1];
    const float* enc_w = (const float*)d_in[2];
    const float* enc_b = (const float*)d_in[3];
    const float* embed_w = (const float*)d_in[4];
    const float* embed_b = (const float*)d_in[5];
    const float* dense_w = (const float*)d_in[6];
    const float* dense_b = (const float*)d_in[7];
    const float* f1_w = (const float*)d_in[8];
    const float* f1_b = (const float*)d_in[9];
    const float* f2_w = (const float*)d_in[10];
    const float* f2_b = (const float*)d_in[11];
    const float* f3_w = (const float*)d_in[12];
    const float* f3_b = (const float*)d_in[13];

    float* ws = (float*)d_ws;
    float* weff_t = ws;                 // 864
    float* beff = ws + 864;             // 32
    float* c1 = ws + 1024;              // 32*512*512 = 8388608
    float* c2 = c1 + 8388608;
    float* p1 = c2 + 8388608;           // 32*256*256 = 2097152
    float* p2 = p1 + 2097152;
    float* feat = p2 + 2097152;         // 48*256*256 = 3145728
    float* pooled = feat + 3145728;     // 576
    float* f1o = c1;                    // alias: c1 dead after pm512
    float* part = c2;                   // alias: c2 dead after pm512 (4.2M)

    fuse_weights_kernel<<<1, 256, 0, stream>>>(enc_w, enc_b, embed_w, embed_b,
                                               weff_t, beff);
    coding_kernel<<<dim3(32, 64, 2), dim3(16, 16), 0, stream>>>(
        x1, x2, weff_t, beff, c1, c2, p1, p2);
    pm512_pool_kernel<<<dim3(32, 32), dim3(16, 16), 0, stream>>>(c1, c2, feat);
    pm256_kernel<<<dim3(32, 32), dim3(64, 4), 0, stream>>>(p1, p2, feat);
    dense_part_kernel<<<dim3(8, 8, 8), dim3(16, 16), 0, stream>>>(
        p1, p2, dense_w, part);
    dense_reduce_kernel<<<2048, 256, 0, stream>>>(part, dense_b, feat);
    f1_kernel<<<dim3(256, 2), 256, 0, stream>>>(feat, f1_w, f1_b, f1o);
    pool3_kernel<<<576, 256, 0, stream>>>(f1o, pooled);
    final_kernel<<<1, 128, 0, stream>>>(pooled, f2_w, f2_b, f3_w, f3_b,
                                        (float*)d_out);
}

// Round 7
// 222.909 us; speedup vs baseline: 7.5610x; 1.0563x over previous
//
#include <hip/hip_runtime.h>
#include <math.h>

// ---------------------------------------------------------------------------
// MyNet: two 1024x1024x3 images -> 3x3 matrix.
// R7: coding was LDS-pipe-bound (216 ds_read_b128/thread ~= 69us of LDS pipe
//     vs 23us FMA). Weights now read as wave-uniform global loads (s_load ->
//     SGPR operand fma), LDS use deleted; ci-outer, all-32-channel acc.
//     pm512: vertical src-pair per thread (24 loads vs 40 per ch), in-thread
//     vertical pool, shfl horizontal pool.
// ---------------------------------------------------------------------------

__global__ void fuse_weights_kernel(const float* __restrict__ enc_w,
                                    const float* __restrict__ enc_b,
                                    const float* __restrict__ embed_w,
                                    const float* __restrict__ embed_b,
                                    float* __restrict__ weff_t,
                                    float* __restrict__ beff) {
    int t = threadIdx.x;
    for (int idx = t; idx < 27 * 32; idx += blockDim.x) {
        int r = idx >> 5, o = idx & 31;
        float s = 0.f;
        for (int k = 0; k < 24; ++k) s += embed_w[o * 24 + k] * enc_w[k * 27 + r];
        weff_t[idx] = s;
    }
    if (t < 32) {
        float s = embed_b[t];
        for (int k = 0; k < 24; ++k) s += embed_w[t * 24 + k] * enc_b[k];
        beff[t] = s;
    }
}

// Fused enc+embed 3x3 conv (3->32) at 1024 res + maxpool2 -> c (512^2)
// + maxpool2 -> p (256^2), pools via shfl. Weights via wave-uniform loads
// (SGPR), no LDS. Thread: conv at (Y, X0) and (Y, X0+1).
__global__ __launch_bounds__(256) void coding_kernel(
    const float* __restrict__ x1, const float* __restrict__ x2,
    const float* __restrict__ weff_t, const float* __restrict__ beff,
    float* __restrict__ c1, float* __restrict__ c2,
    float* __restrict__ p1, float* __restrict__ p2) {
    int tx = threadIdx.x, ty = threadIdx.y;
    int img = blockIdx.z;
    const float* x = img ? x2 : x1;
    float* c = img ? c2 : c1;
    float* p = img ? p2 : p1;
    int Y = blockIdx.y * 16 + ty;   // src row 0..1023
    int cx = blockIdx.x * 16 + tx;  // c col 0..511
    int X0 = 2 * cx;
    bool interior = (blockIdx.y > 0 && blockIdx.y < 63 &&
                     blockIdx.x > 0 && blockIdx.x < 31);
    float acc0[32], acc1[32];
#pragma unroll
    for (int o = 0; o < 32; ++o) {
        acc0[o] = beff[o];
        acc1[o] = acc0[o];
    }
#pragma unroll 1
    for (int ci = 0; ci < 3; ++ci) {
        float in[3][4];
        const float* xc = x + ci * 1048576;
        if (interior) {
#pragma unroll
            for (int r = 0; r < 3; ++r) {
                const float* row = xc + (Y - 1 + r) * 1024 + X0 - 1;
#pragma unroll
                for (int q = 0; q < 4; ++q) in[r][q] = row[q];
            }
        } else {
#pragma unroll
            for (int r = 0; r < 3; ++r)
#pragma unroll
                for (int q = 0; q < 4; ++q) {
                    int gy = Y - 1 + r, gx = X0 - 1 + q;
                    in[r][q] = (gy >= 0 && gy < 1024 && gx >= 0 && gx < 1024)
                                   ? xc[gy * 1024 + gx]
                                   : 0.f;
                }
        }
#pragma unroll
        for (int ky = 0; ky < 3; ++ky)
#pragma unroll
            for (int kx = 0; kx < 3; ++kx) {
                const float* wrow = weff_t + (ci * 9 + ky * 3 + kx) * 32;
                float xa = in[ky][kx];
                float xb = in[ky][kx + 1];
#pragma unroll
                for (int o = 0; o < 32; ++o) {
                    float wv = wrow[o];  // wave-uniform -> s_load / SGPR
                    acc0[o] = fmaf(wv, xa, acc0[o]);
                    acc1[o] = fmaf(wv, xb, acc1[o]);
                }
            }
    }
    int cpix = (Y >> 1) * 512 + cx;
    int ppix = (Y >> 2) * 256 + (cx >> 1);
    bool cwrite = ((ty & 1) == 0);
    bool pwrite = ((ty & 3) == 0) && ((tx & 1) == 0);
#pragma unroll
    for (int o = 0; o < 32; ++o) {
        float m = fmaxf(acc0[o], acc1[o]);     // horizontal src pair
        m = fmaxf(m, __shfl_xor(m, 16, 64));   // vertical src pair -> c
        if (cwrite) c[o * 262144 + cpix] = m;
        float v = fmaxf(m, __shfl_xor(m, 1, 64));   // c-col pair
        v = fmaxf(v, __shfl_xor(v, 32, 64));        // c-row pair -> p
        if (pwrite) p[o * 65536 + ppix] = v;
    }
}

// pixel_match at 512 res + fused maxpool2 -> feat ch0..19.
// One thread per vertical src-row pair (one output px column contribution):
// 4x3 patch per ch per img; vertical pool in-thread, horizontal via shfl.
__global__ __launch_bounds__(256) void pm512_pool_kernel(
    const float* __restrict__ c1, const float* __restrict__ c2,
    float* __restrict__ feat) {
    int tx = threadIdx.x, ty = threadIdx.y;
    int sw = blockIdx.x * 16 + tx;   // src col 0..511
    int rp = blockIdx.y * 16 + ty;   // row pair 0..255
    int sh0 = 2 * rp, sh1 = sh0 + 1;
    int r0 = (sh0 >= 1) ? sh0 - 1 : 0;
    int r3 = (sh1 <= 510) ? sh1 + 1 : 511;
    int cm = (sw >= 1) ? sw - 1 : 0;
    int cp = (sw <= 510) ? sw + 1 : 511;
    float a[2][2][9];
#pragma unroll
    for (int pos = 0; pos < 2; ++pos)
#pragma unroll
        for (int dd = 0; dd < 2; ++dd)
#pragma unroll
            for (int k = 0; k < 9; ++k) a[pos][dd][k] = 0.f;
    const float* b1 = c1;
    const float* b2 = c2;
    const int rows[4] = {r0, sh0, sh1, r3};
    for (int ch = 0; ch < 32; ++ch) {
        float q1[4][3], q2[4][3];
#pragma unroll
        for (int r = 0; r < 4; ++r) {
            const float* rb1 = b1 + rows[r] * 512;
            const float* rb2 = b2 + rows[r] * 512;
            q1[r][0] = rb1[cm];
            q1[r][1] = rb1[sw];
            q1[r][2] = rb1[cp];
            q2[r][0] = rb2[cm];
            q2[r][1] = rb2[sw];
            q2[r][2] = rb2[cp];
        }
#pragma unroll
        for (int pos = 0; pos < 2; ++pos) {
            float y1 = q1[pos + 1][1], y2 = q2[pos + 1][1];
#pragma unroll
            for (int dh = 0; dh < 3; ++dh)
#pragma unroll
                for (int dw = 0; dw < 3; ++dw) {
                    int k = dh * 3 + dw;
                    float t1 = q1[pos + dh][dw] - y2;
                    float t2 = q2[pos + dh][dw] - y1;
                    a[pos][0][k] = fmaf(t1, t1, a[pos][0][k]);
                    a[pos][1][k] = fmaf(t2, t2, a[pos][1][k]);
                }
        }
        b1 += 262144;
        b2 += 262144;
    }
    float d[20];
#pragma unroll
    for (int pos = 0; pos < 2; ++pos) {
        int sh = sh0 + pos;
        float e1[9], e2[9];
        if (sh >= 1 && sh <= 510 && sw >= 1 && sw <= 510) {
            float s1 = 0.f, s2 = 0.f;
#pragma unroll
            for (int k = 0; k < 9; ++k) {
                e1[k] = 1.0f / sqrtf(a[pos][0][k] + 0.01f);
                e2[k] = 1.0f / sqrtf(a[pos][1][k] + 0.01f);
                s1 += e1[k];
                s2 += e2[k];
            }
            float i1 = 1.0f / s1, i2 = 1.0f / s2;
#pragma unroll
            for (int k = 0; k < 9; ++k) {
                e1[k] *= i1;
                e2[k] *= i2;
            }
        } else {
#pragma unroll
            for (int k = 0; k < 9; ++k) {
                e1[k] = 1.0f / 9.0f;
                e2[k] = 1.0f / 9.0f;
            }
        }
        if (pos == 0) {
#pragma unroll
            for (int k = 0; k < 9; ++k) {
                d[k] = e1[k];
                d[9 + k] = e2[k];
            }
        } else {
#pragma unroll
            for (int k = 0; k < 9; ++k) {
                d[k] = fmaxf(d[k], e1[k]);
                d[9 + k] = fmaxf(d[9 + k], e2[k]);
            }
        }
    }
#pragma unroll
    for (int k = 0; k < 18; ++k) d[k] = fmaxf(d[k], __shfl_xor(d[k], 1, 64));
    d[18] = 2.0f * sh1 / 511.0f - 1.0f;         // max ph of the row pair
    d[19] = 2.0f * (sw | 1) / 511.0f - 1.0f;    // max pw of the col pair
    if ((tx & 1) == 0) {
        int pix = rp * 256 + (sw >> 1);
#pragma unroll
        for (int k = 0; k < 20; ++k) feat[k * 65536 + pix] = d[k];
    }
}

// pixel_match at 256 res -> feat ch20..39. Channel-split 4 ways + LDS reduce.
__global__ __launch_bounds__(256) void pm256_kernel(
    const float* __restrict__ p1, const float* __restrict__ p2,
    float* __restrict__ feat) {
    __shared__ float part[4][64][19];
    int lane = threadIdx.x, grp = threadIdx.y;
    int w = blockIdx.x * 8 + (lane & 7);
    int h = blockIdx.y * 8 + (lane >> 3);
    bool interior = (h >= 1 && h <= 254 && w >= 1 && w <= 254);
    float a1[9], a2[9];
#pragma unroll
    for (int k = 0; k < 9; ++k) { a1[k] = 0.f; a2[k] = 0.f; }
    if (interior) {
        int ctr = h * 256 + w;
        for (int c = grp * 8; c < grp * 8 + 8; ++c) {
            const float* b1 = p1 + c * 65536;
            const float* b2 = p2 + c * 65536;
            float y1 = b1[ctr], y2 = b2[ctr];
#pragma unroll
            for (int dh = 0; dh < 3; ++dh)
#pragma unroll
                for (int dw = 0; dw < 3; ++dw) {
                    int off = (h + dh - 1) * 256 + (w + dw - 1);
                    float n1 = b1[off], n2 = b2[off];
                    float t1 = n1 - y2, t2 = n2 - y1;
                    a1[dh * 3 + dw] = fmaf(t1, t1, a1[dh * 3 + dw]);
                    a2[dh * 3 + dw] = fmaf(t2, t2, a2[dh * 3 + dw]);
                }
        }
    }
#pragma unroll
    for (int k = 0; k < 9; ++k) {
        part[grp][lane][k] = a1[k];
        part[grp][lane][k + 9] = a2[k];
    }
    __syncthreads();
    if (grp == 0) {
        int pix = h * 256 + w;
        if (interior) {
            float d1[9], d2[9];
            float s1 = 0.f, s2 = 0.f;
#pragma unroll
            for (int k = 0; k < 9; ++k) {
                float t1 = part[0][lane][k] + part[1][lane][k] +
                           part[2][lane][k] + part[3][lane][k];
                float t2 = part[0][lane][k + 9] + part[1][lane][k + 9] +
                           part[2][lane][k + 9] + part[3][lane][k + 9];
                d1[k] = 1.0f / sqrtf(t1 + 0.01f);
                d2[k] = 1.0f / sqrtf(t2 + 0.01f);
                s1 += d1[k];
                s2 += d2[k];
            }
            float i1 = 1.0f / s1, i2 = 1.0f / s2;
#pragma unroll
            for (int k = 0; k < 9; ++k) {
                feat[(20 + k) * 65536 + pix] = d1[k] * i1;
                feat[(29 + k) * 65536 + pix] = d2[k] * i2;
            }
        } else {
#pragma unroll
            for (int k = 0; k < 18; ++k)
                feat[(20 + k) * 65536 + pix] = 1.0f / 9.0f;
        }
        feat[38 * 65536 + pix] = 2.0f * h / 255.0f - 1.0f;
        feat[39 * 65536 + pix] = 2.0f * w / 255.0f - 1.0f;
    }
}

// Dense conv5x5 partial sums: grid (8,8,8); z = ci group (4 channels).
__global__ __launch_bounds__(256) void dense_part_kernel(
    const float* __restrict__ p1, const float* __restrict__ p2,
    const float* __restrict__ dw, float* __restrict__ part) {
    __shared__ float sdiff[4 * 1296];   // [4][36][36]
    __shared__ float sw[4 * 8 * 28];    // [ci][o][28]
    int tx = threadIdx.x, ty = threadIdx.y;
    int tid = ty * 16 + tx;
    int bz = blockIdx.z;
    int h0 = blockIdx.y * 32, w0 = blockIdx.x * 32;
    for (int idx = tid; idx < 4 * 1296; idx += 256) {
        int ci = idx / 1296, r = idx % 1296;
        int yy = r / 36, xx = r % 36;
        int gy = h0 + yy - 2, gx = w0 + xx - 2;
        float v = 0.f;
        if (gy >= 0 && gy < 256 && gx >= 0 && gx < 256) {
            int g = (bz * 4 + ci) * 65536 + gy * 256 + gx;
            v = p1[g] - p2[g];
        }
        sdiff[idx] = v;
    }
    for (int idx = tid; idx < 4 * 8 * 28; idx += 256) {
        int ci = idx / 224, r = idx % 224;
        int o = r / 28, k = r % 28;
        sw[idx] = (k < 25) ? dw[o * 800 + (bz * 4 + ci) * 25 + k] : 0.f;
    }
    __syncthreads();
    float acc[4][8];
#pragma unroll
    for (int pq = 0; pq < 4; ++pq)
#pragma unroll
        for (int o = 0; o < 8; ++o) acc[pq][o] = 0.f;
    for (int ci = 0; ci < 4; ++ci) {
        float patch[6][6];
#pragma unroll
        for (int yy = 0; yy < 6; ++yy) {
            const float* rowp = &sdiff[ci * 1296 + (2 * ty + yy) * 36 + 2 * tx];
#pragma unroll
            for (int cpair = 0; cpair < 3; ++cpair) {
                float2 lp = *(const float2*)&rowp[2 * cpair];
                patch[yy][2 * cpair] = lp.x;
                patch[yy][2 * cpair + 1] = lp.y;
            }
        }
#pragma unroll
        for (int o = 0; o < 8; ++o) {
            float wreg[28];
            const float4* wp = (const float4*)&sw[(ci * 8 + o) * 28];
#pragma unroll
            for (int q = 0; q < 7; ++q) {
                float4 wv = wp[q];
                wreg[4 * q] = wv.x;
                wreg[4 * q + 1] = wv.y;
                wreg[4 * q + 2] = wv.z;
                wreg[4 * q + 3] = wv.w;
            }
#pragma unroll
            for (int ky = 0; ky < 5; ++ky)
#pragma unroll
                for (int kx = 0; kx < 5; ++kx) {
                    float wv = wreg[ky * 5 + kx];
#pragma unroll
                    for (int pq = 0; pq < 4; ++pq)
                        acc[pq][o] = fmaf(
                            wv, patch[ky + (pq >> 1)][kx + (pq & 1)], acc[pq][o]);
                }
        }
    }
#pragma unroll
    for (int pq = 0; pq < 4; ++pq) {
        int h = h0 + 2 * ty + (pq >> 1), w = w0 + 2 * tx + (pq & 1);
        int pix = h * 256 + w;
#pragma unroll
        for (int o = 0; o < 8; ++o)
            part[bz * 524288 + o * 65536 + pix] = acc[pq][o];
    }
}

// Reduce 8 partials + bias + leaky_relu -> feat ch40..47.
__global__ __launch_bounds__(256) void dense_reduce_kernel(
    const float* __restrict__ part, const float* __restrict__ db,
    float* __restrict__ feat) {
    int idx = blockIdx.x * 256 + threadIdx.x;
    int o = idx >> 16;
    float s = db[o];
#pragma unroll
    for (int z = 0; z < 8; ++z) s += part[z * 524288 + idx];
    float v = (s >= 0.f) ? s : 0.01f * s;
    feat[40 * 65536 + idx] = v;
}

// 1x1 conv 48->64, o-split 2 ways: grid (256,2), 32 outputs each.
__global__ __launch_bounds__(256) void f1_kernel(
    const float* __restrict__ feat, const float* __restrict__ f1w,
    const float* __restrict__ f1b, float* __restrict__ out) {
    __shared__ float sw[1536];
    __shared__ float sb[32];
    int og = blockIdx.y;
    int tid = threadIdx.x;
    for (int i = tid; i < 1536; i += 256) sw[i] = f1w[og * 1536 + i];
    if (tid < 32) sb[tid] = f1b[og * 32 + tid];
    __syncthreads();
    int pix = blockIdx.x * 256 + tid;
    float f[48];
#pragma unroll
    for (int c = 0; c < 48; ++c) f[c] = feat[c * 65536 + pix];
#pragma unroll
    for (int o = 0; o < 32; ++o) {
        float a = sb[o];
        const float4* wv = (const float4*)&sw[o * 48];
#pragma unroll
        for (int c4 = 0; c4 < 12; ++c4) {
            float4 ww = wv[c4];
            a = fmaf(ww.x, f[c4 * 4], a);
            a = fmaf(ww.y, f[c4 * 4 + 1], a);
            a = fmaf(ww.z, f[c4 * 4 + 2], a);
            a = fmaf(ww.w, f[c4 * 4 + 3], a);
        }
        out[(og * 32 + o) * 65536 + pix] = a;
    }
}

// adaptive_max_pool3: one block per (channel, i, j); overlapping regions.
__global__ __launch_bounds__(256) void pool3_kernel(
    const float* __restrict__ f1out, float* __restrict__ pooled) {
    int b = blockIdx.x;  // 64*9
    int c = b / 9, ij = b % 9, i = ij / 3, j = ij % 3;
    int hs = (i * 256) / 3, he = ((i + 1) * 256 + 2) / 3;
    int ws = (j * 256) / 3, we = ((j + 1) * 256 + 2) / 3;
    const float* src = f1out + c * 65536;
    int nh = he - hs, nw = we - ws, tot = nh * nw;
    float m = -INFINITY;
    for (int t = threadIdx.x; t < tot; t += 256) {
        int r = t / nw, q = t - r * nw;
        m = fmaxf(m, src[(hs + r) * 256 + (ws + q)]);
    }
    for (int off = 32; off > 0; off >>= 1) m = fmaxf(m, __shfl_down(m, off, 64));
    __shared__ float red[4];
    if ((threadIdx.x & 63) == 0) red[threadIdx.x >> 6] = m;
    __syncthreads();
    if (threadIdx.x == 0)
        pooled[b] = fmaxf(fmaxf(red[0], red[1]), fmaxf(red[2], red[3]));
}

// f2 conv (64,3,3)->128, L2-normalize, f3 matmul -> 6, assemble 3x3 output.
__global__ __launch_bounds__(128) void final_kernel(
    const float* __restrict__ pooled, const float* __restrict__ f2w,
    const float* __restrict__ f2b, const float* __restrict__ f3w,
    const float* __restrict__ f3b, float* __restrict__ out) {
    __shared__ float xn[128];
    __shared__ float red[2];
    __shared__ float ov[6];
    int t = threadIdx.x;
    float a = f2b[t];
    for (int c = 0; c < 64; ++c)
#pragma unroll
        for (int k = 0; k < 9; ++k)
            a = fmaf(f2w[t * 576 + c * 9 + k], pooled[c * 9 + k], a);
    float sq = a * a;
    for (int off = 32; off > 0; off >>= 1) sq += __shfl_down(sq, off, 64);
    if ((t & 63) == 0) red[t >> 6] = sq;
    __syncthreads();
    float tmp = red[0] + red[1] + 0.001f;
    float scale = 1.0f / sqrtf(tmp);
    xn[t] = a * scale;
    __syncthreads();
    if (t < 6) {
        float o = f3b[t];
        for (int k = 0; k < 128; ++k) o = fmaf(f3w[t * 128 + k], xn[k], o);
        ov[t] = o;
    }
    __syncthreads();
    if (t < 9) {
        int r = t / 3, cc = t % 3;
        float v = 0.f;
        if (r < 2) {
            float x = ov[r * 3 + cc];
            float cl = fminf(fmaxf(x, -0.11f), 0.11f);
            v = cl + 0.01f * x;
        }
        if (r == cc) v += 1.0f;
        out[t] = v;
    }
}

extern "C" void kernel_launch(void* const* d_in, const int* in_sizes, int n_in,
                              void* d_out, int out_size, void* d_ws,
                              size_t ws_size, hipStream_t stream) {
    const float* x1 = (const float*)d_in[0];
    const float* x2 = (const float*)d_in[1];
    const float* enc_w = (const float*)d_in[2];
    const float* enc_b = (const float*)d_in[3];
    const float* embed_w = (const float*)d_in[4];
    const float* embed_b = (const float*)d_in[5];
    const float* dense_w = (const float*)d_in[6];
    const float* dense_b = (const float*)d_in[7];
    const float* f1_w = (const float*)d_in[8];
    const float* f1_b = (const float*)d_in[9];
    const float* f2_w = (const float*)d_in[10];
    const float* f2_b = (const float*)d_in[11];
    const float* f3_w = (const float*)d_in[12];
    const float* f3_b = (const float*)d_in[13];

    float* ws = (float*)d_ws;
    float* weff_t = ws;                 // 864
    float* beff = ws + 864;             // 32
    float* c1 = ws + 1024;              // 32*512*512 = 8388608
    float* c2 = c1 + 8388608;
    float* p1 = c2 + 8388608;           // 32*256*256 = 2097152
    float* p2 = p1 + 2097152;
    float* feat = p2 + 2097152;         // 48*256*256 = 3145728
    float* pooled = feat + 3145728;     // 576
    float* f1o = c1;                    // alias: c1 dead after pm512
    float* part = c2;                   // alias: c2 dead after pm512 (4.2M)

    fuse_weights_kernel<<<1, 256, 0, stream>>>(enc_w, enc_b, embed_w, embed_b,
                                               weff_t, beff);
    coding_kernel<<<dim3(32, 64, 2), dim3(16, 16), 0, stream>>>(
        x1, x2, weff_t, beff, c1, c2, p1, p2);
    pm512_pool_kernel<<<dim3(32, 16), dim3(16, 16), 0, stream>>>(c1, c2, feat);
    pm256_kernel<<<dim3(32, 32), dim3(64, 4), 0, stream>>>(p1, p2, feat);
    dense_part_kernel<<<dim3(8, 8, 8), dim3(16, 16), 0, stream>>>(
        p1, p2, dense_w, part);
    dense_reduce_kernel<<<2048, 256, 0, stream>>>(part, dense_b, feat);
    f1_kernel<<<dim3(256, 2), 256, 0, stream>>>(feat, f1_w, f1_b, f1o);
    pool3_kernel<<<576, 256, 0, stream>>>(f1o, pooled);
    final_kernel<<<1, 128, 0, stream>>>(pooled, f2_w, f2_b, f3_w, f3_b,
                                        (float*)d_out);
}